// Round 8
// baseline (509.395 us; speedup 1.0000x reference)
//
#include <hip/hip_runtime.h>

#define B_    1024
#define NIN_  126
#define NOUT_ 126
#define K_    3
#define H1_   256
#define H2_   256
#define RPB   4
#define TPB   512    // 8 waves, 1 block/CU, grid = 256
#define DIAG_ITERS 32

__device__ __forceinline__ float elu1(float v) { return v > 0.0f ? v : expm1f(v); }

// DPP quad_perm add (VALU pipe)
template<int CTRL>
__device__ __forceinline__ float dpp_add(float v) {
    int s = __builtin_amdgcn_update_dpp(0, __float_as_int(v), CTRL, 0xF, 0xF, true);
    return v + __int_as_float(s);
}
// sum over 8 consecutive lanes: xor1,xor2 via DPP, xor4 via ds_swizzle
__device__ __forceinline__ float qsum8(float v) {
    v = dpp_add<0xB1>(v);
    v = dpp_add<0x4E>(v);
    int s = __builtin_amdgcn_ds_swizzle(__float_as_int(v), 0x101F);
    return v + __int_as_float(s);
}

// barrier draining only LDS/SMEM ops; global loads stay in flight
__device__ __forceinline__ void barrier_lds() {
    asm volatile("s_waitcnt lgkmcnt(0)\n\ts_barrier" ::: "memory");
}

// runtime zero the compiler cannot see through (defeats load hoisting in loops)
__device__ __forceinline__ int opaque_zero() {
    int z;
    asm volatile("v_mov_b32 %0, 0" : "=v"(z));
    return z;
}

// ============================ REAL KERNEL (frozen round-7) ============================
__global__ __launch_bounds__(TPB) void bim_fused(
    const float* __restrict__ x,  const float* __restrict__ W0,
    const float* __restrict__ b0, const float* __restrict__ W1,
    const float* __restrict__ b1, const float* __restrict__ W2,
    const float* __restrict__ b2, const int*  __restrict__ iidx,
    const int*  __restrict__ oidx, float* __restrict__ out)
{
    __shared__ float xe [RPB][128];
    __shared__ float h1s[RPB][H1_];
    __shared__ float h2s[RPB][H2_];
    __shared__ float ts [RPB][128];

    const int tid  = threadIdx.x;
    const int row0 = blockIdx.x * RPB;
    const int q    = tid & 7;
    const int g    = tid >> 3;

    int aj0, aj1, aj2, ar0, ar1, ar2; float ax0, ax1, ax2;
    {
        const int n0 = tid;
        ar0 = n0 / (NIN_ * K_); const int m0 = n0 - ar0 * (NIN_ * K_);
        aj0 = iidx[(row0 + ar0) * (NIN_ * K_) + m0];
        ax0 = x[(row0 + ar0) * NIN_ + m0 / K_];
        const int n1 = tid + TPB;
        ar1 = n1 / (NIN_ * K_); const int m1 = n1 - ar1 * (NIN_ * K_);
        aj1 = iidx[(row0 + ar1) * (NIN_ * K_) + m1];
        ax1 = x[(row0 + ar1) * NIN_ + m1 / K_];
        const int n2 = tid + 2 * TPB;
        const int n2c = n2 < RPB * NIN_ * K_ ? n2 : 0;
        ar2 = n2c / (NIN_ * K_); const int m2 = n2c - ar2 * (NIN_ * K_);
        aj2 = iidx[(row0 + ar2) * (NIN_ * K_) + m2];
        ax2 = x[(row0 + ar2) * NIN_ + m2 / K_];
        if (n2 >= RPB * NIN_ * K_) aj2 = NIN_;
    }

    const float* wb = W0 + (g * 4) * NIN_;
    float2 wA[4][4], wB[4][4];
    #pragma unroll
    for (int jj = 0; jj < 4; ++jj) {
        const int j  = q * 4 + jj * 32;
        const int j2 = (j + 2 > NIN_ - 2) ? (NIN_ - 2) : (j + 2);
        #pragma unroll
        for (int oo = 0; oo < 4; ++oo) {
            wA[jj][oo] = *reinterpret_cast<const float2*>(wb + oo * NIN_ + j);
            wB[jj][oo] = *reinterpret_cast<const float2*>(wb + oo * NIN_ + j2);
        }
    }

    int ej0, ej1, ej2;
    {
        const int t = tid < RPB * NOUT_ ? tid : 0;
        const int r = t / NOUT_, o = t - r * NOUT_;
        const int base = (row0 + r) * (NOUT_ * K_) + o * K_;
        ej0 = oidx[base]; ej1 = oidx[base + 1]; ej2 = oidx[base + 2];
    }
    const float4 b0v = *reinterpret_cast<const float4*>(b0 + g * 4);
    const float4 b1v = *reinterpret_cast<const float4*>(b1 + g * 4);
    const int    gD  = (g < 63) ? g : 0;
    const float2 b2v = *reinterpret_cast<const float2*>(b2 + gD * 2);

    (&xe[0][0])[tid] = 0.0f;
    barrier_lds();
    if (aj0 < NIN_) atomicAdd(&xe[ar0][aj0], ax0);
    if (aj1 < NIN_) atomicAdd(&xe[ar1][aj1], ax1);
    if (aj2 < NIN_) atomicAdd(&xe[ar2][aj2], ax2);

    const float* wcp = W1 + (g * 4) * H1_ + q * 4;
    float4 wc1[4][4];
    #pragma unroll
    for (int jj = 0; jj < 4; ++jj)
        #pragma unroll
        for (int oo = 0; oo < 4; ++oo)
            wc1[jj][oo] = *reinterpret_cast<const float4*>(wcp + oo * H1_ + jj * 32);
    barrier_lds();

    float4 wc2[4][4];
    {
        float acc[4][4] = {};
        #pragma unroll
        for (int jj = 0; jj < 2; ++jj) {
            const int j = q * 4 + jj * 32;
            float4 a[RPB];
            #pragma unroll
            for (int r = 0; r < RPB; ++r)
                a[r] = *reinterpret_cast<const float4*>(&xe[r][j]);
            #pragma unroll
            for (int oo = 0; oo < 4; ++oo)
                #pragma unroll
                for (int r = 0; r < RPB; ++r) {
                    acc[oo][r] = fmaf(wA[jj][oo].x, a[r].x, acc[oo][r]);
                    acc[oo][r] = fmaf(wA[jj][oo].y, a[r].y, acc[oo][r]);
                    acc[oo][r] = fmaf(wB[jj][oo].x, a[r].z, acc[oo][r]);
                    acc[oo][r] = fmaf(wB[jj][oo].y, a[r].w, acc[oo][r]);
                }
        }
        #pragma unroll
        for (int jj = 0; jj < 4; ++jj)
            #pragma unroll
            for (int oo = 0; oo < 4; ++oo)
                wc2[jj][oo] = *reinterpret_cast<const float4*>(wcp + oo * H1_ + (jj + 4) * 32);
        #pragma unroll
        for (int jj = 2; jj < 4; ++jj) {
            const int j = q * 4 + jj * 32;
            float4 a[RPB];
            #pragma unroll
            for (int r = 0; r < RPB; ++r)
                a[r] = *reinterpret_cast<const float4*>(&xe[r][j]);
            #pragma unroll
            for (int oo = 0; oo < 4; ++oo)
                #pragma unroll
                for (int r = 0; r < RPB; ++r) {
                    acc[oo][r] = fmaf(wA[jj][oo].x, a[r].x, acc[oo][r]);
                    acc[oo][r] = fmaf(wA[jj][oo].y, a[r].y, acc[oo][r]);
                    acc[oo][r] = fmaf(wB[jj][oo].x, a[r].z, acc[oo][r]);
                    acc[oo][r] = fmaf(wB[jj][oo].y, a[r].w, acc[oo][r]);
                }
        }
        #pragma unroll
        for (int oo = 0; oo < 4; ++oo)
            #pragma unroll
            for (int r = 0; r < RPB; ++r) acc[oo][r] = qsum8(acc[oo][r]);
        float v0 = acc[0][0], v1 = acc[0][1];
        #pragma unroll
        for (int i = 1; i < 8; ++i) {
            v0 = (q == i) ? acc[(2 * i) >> 2][(2 * i) & 3]         : v0;
            v1 = (q == i) ? acc[(2 * i + 1) >> 2][(2 * i + 1) & 3] : v1;
        }
        const int oo = q >> 1, r0 = (q & 1) * 2;
        const float bias = (oo == 0) ? b0v.x : (oo == 1) ? b0v.y : (oo == 2) ? b0v.z : b0v.w;
        const int o = g * 4 + oo;
        h1s[r0][o]     = elu1(v0 + bias);
        h1s[r0 + 1][o] = elu1(v1 + bias);
    }
    barrier_lds();

    const float* wdp = W2 + (gD * 2) * H2_ + q * 4;
    float4 wd[8][2];
    {
        float acc[4][4] = {};
        #pragma unroll
        for (int jj = 0; jj < 6; ++jj) {
            const float4* wrow = (jj < 4) ? wc1[jj] : wc2[jj - 4];
            const int j = q * 4 + jj * 32;
            float4 a[RPB];
            #pragma unroll
            for (int r = 0; r < RPB; ++r)
                a[r] = *reinterpret_cast<const float4*>(&h1s[r][j]);
            #pragma unroll
            for (int oo = 0; oo < 4; ++oo)
                #pragma unroll
                for (int r = 0; r < RPB; ++r) {
                    acc[oo][r] = fmaf(wrow[oo].x, a[r].x, acc[oo][r]);
                    acc[oo][r] = fmaf(wrow[oo].y, a[r].y, acc[oo][r]);
                    acc[oo][r] = fmaf(wrow[oo].z, a[r].z, acc[oo][r]);
                    acc[oo][r] = fmaf(wrow[oo].w, a[r].w, acc[oo][r]);
                }
        }
        #pragma unroll
        for (int jj = 0; jj < 8; ++jj)
            #pragma unroll
            for (int oo = 0; oo < 2; ++oo)
                wd[jj][oo] = *reinterpret_cast<const float4*>(wdp + oo * H2_ + jj * 32);
        #pragma unroll
        for (int jj = 6; jj < 8; ++jj) {
            const float4* wrow = wc2[jj - 4];
            const int j = q * 4 + jj * 32;
            float4 a[RPB];
            #pragma unroll
            for (int r = 0; r < RPB; ++r)
                a[r] = *reinterpret_cast<const float4*>(&h1s[r][j]);
            #pragma unroll
            for (int oo = 0; oo < 4; ++oo)
                #pragma unroll
                for (int r = 0; r < RPB; ++r) {
                    acc[oo][r] = fmaf(wrow[oo].x, a[r].x, acc[oo][r]);
                    acc[oo][r] = fmaf(wrow[oo].y, a[r].y, acc[oo][r]);
                    acc[oo][r] = fmaf(wrow[oo].z, a[r].z, acc[oo][r]);
                    acc[oo][r] = fmaf(wrow[oo].w, a[r].w, acc[oo][r]);
                }
        }
        #pragma unroll
        for (int oo = 0; oo < 4; ++oo)
            #pragma unroll
            for (int r = 0; r < RPB; ++r) acc[oo][r] = qsum8(acc[oo][r]);
        float v0 = acc[0][0], v1 = acc[0][1];
        #pragma unroll
        for (int i = 1; i < 8; ++i) {
            v0 = (q == i) ? acc[(2 * i) >> 2][(2 * i) & 3]         : v0;
            v1 = (q == i) ? acc[(2 * i + 1) >> 2][(2 * i + 1) & 3] : v1;
        }
        const int oo = q >> 1, r0 = (q & 1) * 2;
        const float bias = (oo == 0) ? b1v.x : (oo == 1) ? b1v.y : (oo == 2) ? b1v.z : b1v.w;
        const int o = g * 4 + oo;
        h2s[r0][o]     = elu1(v0 + bias);
        h2s[r0 + 1][o] = elu1(v1 + bias);
    }
    barrier_lds();

    {
        float acc[2][4] = {};
        #pragma unroll
        for (int jj = 0; jj < 8; ++jj) {
            const int j = q * 4 + jj * 32;
            float4 a[RPB];
            #pragma unroll
            for (int r = 0; r < RPB; ++r)
                a[r] = *reinterpret_cast<const float4*>(&h2s[r][j]);
            #pragma unroll
            for (int oo = 0; oo < 2; ++oo)
                #pragma unroll
                for (int r = 0; r < RPB; ++r) {
                    acc[oo][r] = fmaf(wd[jj][oo].x, a[r].x, acc[oo][r]);
                    acc[oo][r] = fmaf(wd[jj][oo].y, a[r].y, acc[oo][r]);
                    acc[oo][r] = fmaf(wd[jj][oo].z, a[r].z, acc[oo][r]);
                    acc[oo][r] = fmaf(wd[jj][oo].w, a[r].w, acc[oo][r]);
                }
        }
        #pragma unroll
        for (int oo = 0; oo < 2; ++oo)
            #pragma unroll
            for (int r = 0; r < RPB; ++r) acc[oo][r] = qsum8(acc[oo][r]);
        float v = acc[0][0];
        #pragma unroll
        for (int i = 1; i < 8; ++i) v = (q == i) ? acc[i >> 2][i & 3] : v;
        const int oo = q >> 2, rr = q & 3;
        if (g < 63) ts[rr][g * 2 + oo] = v + (oo ? b2v.y : b2v.x);
        else        ts[rr][126 + oo]   = 0.0f;
    }
    barrier_lds();

    if (tid < RPB * NOUT_) {
        const int r = tid / NOUT_, o = tid - r * NOUT_;
        out[(row0 + r) * NOUT_ + o] = ts[r][ej0] + ts[r][ej1] + ts[r][ej2];
    }
}

// ============================ DIAGNOSTICS (looped x32, write d_ws only) ============================

// phase A mirror: zero + index/x loads + LDS atomics
__global__ __launch_bounds__(TPB) void diag_phaseA(
    const float* __restrict__ x, const int* __restrict__ iidx, float* __restrict__ ws)
{
    __shared__ float xe[RPB][128];
    const int tid = threadIdx.x;
    const int row0 = blockIdx.x * RPB;
    float sink = 0.f;
    for (int it = 0; it < DIAG_ITERS; ++it) {
        (&xe[0][0])[tid] = 0.0f;
        barrier_lds();
        const int z = opaque_zero();
        int aj[3], ar[3]; float ax[3];
        #pragma unroll
        for (int u = 0; u < 3; ++u) {
            const int n = tid + u * TPB;
            const int nc = n < RPB * NIN_ * K_ ? n : 0;
            ar[u] = nc / (NIN_ * K_);
            const int m = nc - ar[u] * (NIN_ * K_);
            aj[u] = iidx[(row0 + ar[u]) * (NIN_ * K_) + m + z];
            ax[u] = x[(row0 + ar[u]) * NIN_ + m / K_ + z];
            if (n >= RPB * NIN_ * K_) aj[u] = NIN_;
        }
        #pragma unroll
        for (int u = 0; u < 3; ++u)
            if (aj[u] < NIN_) atomicAdd(&xe[ar[u]][aj[u]], ax[u]);
        barrier_lds();
        sink += xe[tid & 3][(tid + it) & 127];
        barrier_lds();
    }
    ws[(size_t)blockIdx.x * TPB + tid] = sink;
}

// phase B mirror: W0 loads (float2 pattern) + FMAs vs LDS + qsum8 + LDS write
__global__ __launch_bounds__(TPB) void diag_phaseB(
    const float* __restrict__ W0, float* __restrict__ ws)
{
    __shared__ float xe[RPB][128];
    __shared__ float h1s[RPB][H1_];
    const int tid = threadIdx.x, q = tid & 7, g = tid >> 3;
    (&xe[0][0])[tid] = 0.001f * (float)tid;
    __syncthreads();
    float sink = 0.f;
    const float* wb0 = W0 + (g * 4) * NIN_;
    for (int it = 0; it < DIAG_ITERS; ++it) {
        const float* wbp = wb0 + opaque_zero();
        float2 wA[4][4], wB[4][4];
        #pragma unroll
        for (int jj = 0; jj < 4; ++jj) {
            const int j  = q * 4 + jj * 32;
            const int j2 = (j + 2 > NIN_ - 2) ? (NIN_ - 2) : (j + 2);
            #pragma unroll
            for (int oo = 0; oo < 4; ++oo) {
                wA[jj][oo] = *reinterpret_cast<const float2*>(wbp + oo * NIN_ + j);
                wB[jj][oo] = *reinterpret_cast<const float2*>(wbp + oo * NIN_ + j2);
            }
        }
        float acc[4][4] = {};
        #pragma unroll
        for (int jj = 0; jj < 4; ++jj) {
            const int j = q * 4 + jj * 32;
            float4 a[RPB];
            #pragma unroll
            for (int r = 0; r < RPB; ++r)
                a[r] = *reinterpret_cast<const float4*>(&xe[r][j]);
            #pragma unroll
            for (int oo = 0; oo < 4; ++oo)
                #pragma unroll
                for (int r = 0; r < RPB; ++r) {
                    acc[oo][r] = fmaf(wA[jj][oo].x, a[r].x, acc[oo][r]);
                    acc[oo][r] = fmaf(wA[jj][oo].y, a[r].y, acc[oo][r]);
                    acc[oo][r] = fmaf(wB[jj][oo].x, a[r].z, acc[oo][r]);
                    acc[oo][r] = fmaf(wB[jj][oo].y, a[r].w, acc[oo][r]);
                }
        }
        #pragma unroll
        for (int oo = 0; oo < 4; ++oo)
            #pragma unroll
            for (int r = 0; r < RPB; ++r) acc[oo][r] = qsum8(acc[oo][r]);
        const float vv = acc[0][0] + acc[1][1] + acc[2][2] + acc[3][3];
        h1s[q & 3][(g * 4 + (q >> 1)) & (H1_ - 1)] = vv;
        barrier_lds();
        sink += h1s[(tid + it) & 3][(tid + it) & (H1_ - 1)];
        barrier_lds();
    }
    ws[(size_t)blockIdx.x * TPB + tid] = sink;
}

// phase C mirror: W1 loads (32x float4) + 512 FMAs + qsum8 x16
__global__ __launch_bounds__(TPB) void diag_phaseC(
    const float* __restrict__ W1, float* __restrict__ ws)
{
    __shared__ float h1s[RPB][H1_];
    __shared__ float h2s[RPB][H2_];
    const int tid = threadIdx.x, q = tid & 7, g = tid >> 3;
    #pragma unroll
    for (int u = 0; u < 2; ++u) (&h1s[0][0])[tid + u * TPB] = 0.001f * (float)tid;
    __syncthreads();
    float sink = 0.f;
    const float* wcp0 = W1 + (g * 4) * H1_ + q * 4;
    for (int it = 0; it < DIAG_ITERS; ++it) {
        const float* wcp = wcp0 + opaque_zero();
        float4 wc[8][4];
        #pragma unroll
        for (int jj = 0; jj < 8; ++jj)
            #pragma unroll
            for (int oo = 0; oo < 4; ++oo)
                wc[jj][oo] = *reinterpret_cast<const float4*>(wcp + oo * H1_ + jj * 32);
        float acc[4][4] = {};
        #pragma unroll
        for (int jj = 0; jj < 8; ++jj) {
            const int j = q * 4 + jj * 32;
            float4 a[RPB];
            #pragma unroll
            for (int r = 0; r < RPB; ++r)
                a[r] = *reinterpret_cast<const float4*>(&h1s[r][j]);
            #pragma unroll
            for (int oo = 0; oo < 4; ++oo)
                #pragma unroll
                for (int r = 0; r < RPB; ++r) {
                    acc[oo][r] = fmaf(wc[jj][oo].x, a[r].x, acc[oo][r]);
                    acc[oo][r] = fmaf(wc[jj][oo].y, a[r].y, acc[oo][r]);
                    acc[oo][r] = fmaf(wc[jj][oo].z, a[r].z, acc[oo][r]);
                    acc[oo][r] = fmaf(wc[jj][oo].w, a[r].w, acc[oo][r]);
                }
        }
        #pragma unroll
        for (int oo = 0; oo < 4; ++oo)
            #pragma unroll
            for (int r = 0; r < RPB; ++r) acc[oo][r] = qsum8(acc[oo][r]);
        const float vv = acc[0][0] + acc[1][1] + acc[2][2] + acc[3][3];
        h2s[q & 3][(g * 4 + (q >> 1)) & (H2_ - 1)] = vv;
        barrier_lds();
        sink += h2s[(tid + it) & 3][(tid + it) & (H2_ - 1)];
        barrier_lds();
    }
    ws[(size_t)blockIdx.x * TPB + tid] = sink;
}

// phase D mirror: W2 loads (16x float4) + 256 FMAs + qsum8 x8
__global__ __launch_bounds__(TPB) void diag_phaseD(
    const float* __restrict__ W2, float* __restrict__ ws)
{
    __shared__ float h2s[RPB][H2_];
    __shared__ float ts[RPB][128];
    const int tid = threadIdx.x, q = tid & 7, g = tid >> 3;
    #pragma unroll
    for (int u = 0; u < 2; ++u) (&h2s[0][0])[tid + u * TPB] = 0.001f * (float)tid;
    __syncthreads();
    float sink = 0.f;
    const int gD = (g < 63) ? g : 0;
    const float* wdp0 = W2 + (gD * 2) * H2_ + q * 4;
    for (int it = 0; it < DIAG_ITERS; ++it) {
        const float* wdp = wdp0 + opaque_zero();
        float4 wd[8][2];
        #pragma unroll
        for (int jj = 0; jj < 8; ++jj)
            #pragma unroll
            for (int oo = 0; oo < 2; ++oo)
                wd[jj][oo] = *reinterpret_cast<const float4*>(wdp + oo * H2_ + jj * 32);
        float acc[2][4] = {};
        #pragma unroll
        for (int jj = 0; jj < 8; ++jj) {
            const int j = q * 4 + jj * 32;
            float4 a[RPB];
            #pragma unroll
            for (int r = 0; r < RPB; ++r)
                a[r] = *reinterpret_cast<const float4*>(&h2s[r][j]);
            #pragma unroll
            for (int oo = 0; oo < 2; ++oo)
                #pragma unroll
                for (int r = 0; r < RPB; ++r) {
                    acc[oo][r] = fmaf(wd[jj][oo].x, a[r].x, acc[oo][r]);
                    acc[oo][r] = fmaf(wd[jj][oo].y, a[r].y, acc[oo][r]);
                    acc[oo][r] = fmaf(wd[jj][oo].z, a[r].z, acc[oo][r]);
                    acc[oo][r] = fmaf(wd[jj][oo].w, a[r].w, acc[oo][r]);
                }
        }
        #pragma unroll
        for (int oo = 0; oo < 2; ++oo)
            #pragma unroll
            for (int r = 0; r < RPB; ++r) acc[oo][r] = qsum8(acc[oo][r]);
        const float vv = acc[0][0] + acc[1][1];
        ts[q & 3][(g * 2 + (q >> 2)) & 127] = vv;
        barrier_lds();
        sink += ts[(tid + it) & 3][(tid + it) & 127];
        barrier_lds();
    }
    ws[(size_t)blockIdx.x * TPB + tid] = sink;
}

// pure per-CU weight stream: every block reads ALL of W0,W1,W2 (float4)
__global__ __launch_bounds__(TPB) void diag_memstream(
    const float* __restrict__ W0, const float* __restrict__ W1,
    const float* __restrict__ W2, float* __restrict__ ws)
{
    const int tid = threadIdx.x;
    const float4* w0v = reinterpret_cast<const float4*>(W0);  // 8064
    const float4* w1v = reinterpret_cast<const float4*>(W1);  // 16384
    const float4* w2v = reinterpret_cast<const float4*>(W2);  // 8064
    float sx = 0.f, sy = 0.f, sz = 0.f, sw = 0.f;
    for (int it = 0; it < DIAG_ITERS; ++it) {
        const int z = opaque_zero();
        for (int i = tid; i < 8064; i += TPB) {
            const float4 v = w0v[i + z];
            sx += v.x; sy += v.y; sz += v.z; sw += v.w;
        }
        for (int i = tid; i < 16384; i += TPB) {
            const float4 v = w1v[i + z];
            sx += v.x; sy += v.y; sz += v.z; sw += v.w;
        }
        for (int i = tid; i < 8064; i += TPB) {
            const float4 v = w2v[i + z];
            sx += v.x; sy += v.y; sz += v.z; sw += v.w;
        }
    }
    ws[(size_t)blockIdx.x * TPB + tid] = sx + sy + sz + sw;
}

extern "C" void kernel_launch(void* const* d_in, const int* in_sizes, int n_in,
                              void* d_out, int out_size, void* d_ws, size_t ws_size,
                              hipStream_t stream) {
    const float* x   = (const float*)d_in[0];
    const float* W0  = (const float*)d_in[1];
    const float* b0  = (const float*)d_in[2];
    const float* W1  = (const float*)d_in[3];
    const float* b1  = (const float*)d_in[4];
    const float* W2  = (const float*)d_in[5];
    const float* b2  = (const float*)d_in[6];
    const int*  iidx = (const int*)d_in[7];
    const int*  oidx = (const int*)d_in[8];
    float* out = (float*)d_out;
    float* ws  = (float*)d_ws;

    // real kernel first (control; produces d_out)
    bim_fused<<<B_ / RPB, TPB, 0, stream>>>(x, W0, b0, W1, b1, W2, b2, iidx, oidx, out);

    // diagnostics (x32 loops; surface in rocprof top-5 with per-phase counters)
    diag_phaseA   <<<B_ / RPB, TPB, 0, stream>>>(x, iidx, ws);
    diag_phaseB   <<<B_ / RPB, TPB, 0, stream>>>(W0, ws);
    diag_phaseC   <<<B_ / RPB, TPB, 0, stream>>>(W1, ws);
    diag_phaseD   <<<B_ / RPB, TPB, 0, stream>>>(W2, ws);
    diag_memstream<<<B_ / RPB, TPB, 0, stream>>>(W0, W1, W2, ws);
}

// Round 9
// 19.817 us; speedup vs baseline: 25.7047x; 25.7047x over previous
//
#include <hip/hip_runtime.h>

#define B_    1024
#define NIN_  126
#define NOUT_ 126
#define K_    3
#define H1_   256
#define H2_   256
#define RPB   4
#define TPB   512    // 8 waves, 1 block/CU, grid = 256

// bf16 weight copies in d_ws (elements, not bytes)
#define W0BF_OFF 0          // [256][128] padded, cols 126/127 = 0
#define W1BF_OFF 32768      // [256][256]
#define W2BF_OFF 98304      // [126][256]
#define WBF_TOTAL 130560

__device__ __forceinline__ float elu1(float v) { return v > 0.0f ? v : expm1f(v); }

// DPP quad_perm add (VALU pipe)
template<int CTRL>
__device__ __forceinline__ float dpp_add(float v) {
    int s = __builtin_amdgcn_update_dpp(0, __float_as_int(v), CTRL, 0xF, 0xF, true);
    return v + __int_as_float(s);
}
// sum over 8 consecutive lanes: xor1,xor2 via DPP, xor4 via ds_swizzle
__device__ __forceinline__ float qsum8(float v) {
    v = dpp_add<0xB1>(v);
    v = dpp_add<0x4E>(v);
    int s = __builtin_amdgcn_ds_swizzle(__float_as_int(v), 0x101F);
    return v + __int_as_float(s);
}

// barrier draining only LDS/SMEM ops; global loads stay in flight
__device__ __forceinline__ void barrier_lds() {
    asm volatile("s_waitcnt lgkmcnt(0)\n\ts_barrier" ::: "memory");
}

// round-to-nearest-even f32 -> bf16
__device__ __forceinline__ unsigned short f2bf(float f) {
    unsigned u = __float_as_uint(f);
    u = (u + 0x7FFFu + ((u >> 16) & 1u)) >> 16;
    return (unsigned short)u;
}
// unpack 2 bf16 (packed in one u32, little-endian) -> 2 floats
__device__ __forceinline__ float2 bf2f(unsigned u) {
    return make_float2(__uint_as_float(u << 16), __uint_as_float(u & 0xFFFF0000u));
}

// ===================== K1: convert weights to bf16 in d_ws =====================
__global__ __launch_bounds__(256) void wconv(
    const float* __restrict__ W0, const float* __restrict__ W1,
    const float* __restrict__ W2, unsigned short* __restrict__ wsb)
{
    const int t = blockIdx.x * 256 + threadIdx.x;   // grid 512 -> 131072 threads
    if (t < 32768) {                                // W0 padded [256][128]
        const int o = t >> 7, j = t & 127;
        wsb[W0BF_OFF + t] = (j < NIN_) ? f2bf(W0[o * NIN_ + j]) : (unsigned short)0;
    } else if (t < 98304) {                         // W1 [256][256]
        const int e = t - 32768;
        wsb[W1BF_OFF + e] = f2bf(W1[e]);
    } else if (t < WBF_TOTAL) {                     // W2 [126][256]
        const int e = t - 98304;
        wsb[W2BF_OFF + e] = f2bf(W2[e]);
    }
}

// ===================== K2: fused MLP, bf16 weight stream =====================
__global__ __launch_bounds__(TPB) void bim_fused(
    const float* __restrict__ x,  const unsigned short* __restrict__ wsb,
    const float* __restrict__ b0, const float* __restrict__ b1,
    const float* __restrict__ b2, const int* __restrict__ iidx,
    const int* __restrict__ oidx, float* __restrict__ out)
{
    __shared__ float xe [RPB][128];   // scattered x; cols 126/127 stay 0
    __shared__ float h1s[RPB][H1_];
    __shared__ float h2s[RPB][H2_];
    __shared__ float ts [RPB][128];   // b2 folded in; cols 126/127 zeroed

    const int tid  = threadIdx.x;
    const int row0 = blockIdx.x * RPB;
    const int q    = tid & 7;    // k-split lane
    const int g    = tid >> 3;   // group 0..63

    // ---- phase-A operands first (phase A critical path) ----
    int aj0, aj1, aj2, ar0, ar1, ar2; float ax0, ax1, ax2;
    {
        const int n0 = tid;
        ar0 = n0 / (NIN_ * K_); const int m0 = n0 - ar0 * (NIN_ * K_);
        aj0 = iidx[(row0 + ar0) * (NIN_ * K_) + m0];
        ax0 = x[(row0 + ar0) * NIN_ + m0 / K_];
        const int n1 = tid + TPB;
        ar1 = n1 / (NIN_ * K_); const int m1 = n1 - ar1 * (NIN_ * K_);
        aj1 = iidx[(row0 + ar1) * (NIN_ * K_) + m1];
        ax1 = x[(row0 + ar1) * NIN_ + m1 / K_];
        const int n2 = tid + 2 * TPB;
        const int n2c = n2 < RPB * NIN_ * K_ ? n2 : 0;
        ar2 = n2c / (NIN_ * K_); const int m2 = n2c - ar2 * (NIN_ * K_);
        aj2 = iidx[(row0 + ar2) * (NIN_ * K_) + m2];
        ax2 = x[(row0 + ar2) * NIN_ + m2 / K_];
        if (n2 >= RPB * NIN_ * K_) aj2 = NIN_;
    }

    // ---- W0 in FULL (32 VGPRs packed), latency covered by phase A ----
    const unsigned short* w0b = wsb + W0BF_OFF + (g * 4) * 128 + q * 4;
    uint2 wb[4][4];   // [jj][oo] = 4 bf16 (cols j..j+3), j = q*4 + jj*32
    #pragma unroll
    for (int jj = 0; jj < 4; ++jj)
        #pragma unroll
        for (int oo = 0; oo < 4; ++oo)
            wb[jj][oo] = *reinterpret_cast<const uint2*>(w0b + oo * 128 + jj * 32);

    // ---- phase-E indices + biases (small) ----
    int ej0, ej1, ej2;
    {
        const int t = tid < RPB * NOUT_ ? tid : 0;
        const int r = t / NOUT_, o = t - r * NOUT_;
        const int base = (row0 + r) * (NOUT_ * K_) + o * K_;
        ej0 = oidx[base]; ej1 = oidx[base + 1]; ej2 = oidx[base + 2];
    }
    const float4 b0v = *reinterpret_cast<const float4*>(b0 + g * 4);
    const float4 b1v = *reinterpret_cast<const float4*>(b1 + g * 4);
    const int    gD  = (g < 63) ? g : 0;
    const float2 b2v = *reinterpret_cast<const float2*>(b2 + gD * 2);

    // ======== phase A: zero xe, barrier, scatter ========
    (&xe[0][0])[tid] = 0.0f;
    barrier_lds();
    if (aj0 < NIN_) atomicAdd(&xe[ar0][aj0], ax0);
    if (aj1 < NIN_) atomicAdd(&xe[ar1][aj1], ax1);
    if (aj2 < NIN_) atomicAdd(&xe[ar2][aj2], ax2);

    // ---- issue W1 FIRST HALF (32 VGPRs packed) before the barrier ----
    const unsigned short* wcp = wsb + W1BF_OFF + (g * 4) * H1_ + q * 4;
    uint2 wc1[4][4];
    #pragma unroll
    for (int jj = 0; jj < 4; ++jj)
        #pragma unroll
        for (int oo = 0; oo < 4; ++oo)
            wc1[jj][oo] = *reinterpret_cast<const uint2*>(wcp + oo * H1_ + jj * 32);
    barrier_lds();

    // ======== phase B: h1 = elu(xe @ W0^T + b0) ========
    uint2 wc2[4][4];   // W1 second half, issued mid-phase
    {
        float acc[4][4] = {};   // [oo][r]
        #pragma unroll
        for (int jj = 0; jj < 2; ++jj) {
            const int j = q * 4 + jj * 32;
            float4 a[RPB];
            #pragma unroll
            for (int r = 0; r < RPB; ++r)
                a[r] = *reinterpret_cast<const float4*>(&xe[r][j]);
            #pragma unroll
            for (int oo = 0; oo < 4; ++oo) {
                const float2 p0 = bf2f(wb[jj][oo].x);
                const float2 p1 = bf2f(wb[jj][oo].y);
                #pragma unroll
                for (int r = 0; r < RPB; ++r) {
                    acc[oo][r] = fmaf(p0.x, a[r].x, acc[oo][r]);
                    acc[oo][r] = fmaf(p0.y, a[r].y, acc[oo][r]);
                    acc[oo][r] = fmaf(p1.x, a[r].z, acc[oo][r]);
                    acc[oo][r] = fmaf(p1.y, a[r].w, acc[oo][r]);
                }
            }
        }
        // ---- issue W1 SECOND HALF (32 VGPRs packed) ----
        #pragma unroll
        for (int jj = 0; jj < 4; ++jj)
            #pragma unroll
            for (int oo = 0; oo < 4; ++oo)
                wc2[jj][oo] = *reinterpret_cast<const uint2*>(wcp + oo * H1_ + (jj + 4) * 32);
        #pragma unroll
        for (int jj = 2; jj < 4; ++jj) {
            const int j = q * 4 + jj * 32;
            float4 a[RPB];
            #pragma unroll
            for (int r = 0; r < RPB; ++r)
                a[r] = *reinterpret_cast<const float4*>(&xe[r][j]);
            #pragma unroll
            for (int oo = 0; oo < 4; ++oo) {
                const float2 p0 = bf2f(wb[jj][oo].x);
                const float2 p1 = bf2f(wb[jj][oo].y);
                #pragma unroll
                for (int r = 0; r < RPB; ++r) {
                    acc[oo][r] = fmaf(p0.x, a[r].x, acc[oo][r]);
                    acc[oo][r] = fmaf(p0.y, a[r].y, acc[oo][r]);
                    acc[oo][r] = fmaf(p1.x, a[r].z, acc[oo][r]);
                    acc[oo][r] = fmaf(p1.y, a[r].w, acc[oo][r]);
                }
            }
        }
        #pragma unroll
        for (int oo = 0; oo < 4; ++oo)
            #pragma unroll
            for (int r = 0; r < RPB; ++r) acc[oo][r] = qsum8(acc[oo][r]);
        float v0 = acc[0][0], v1 = acc[0][1];
        #pragma unroll
        for (int i = 1; i < 8; ++i) {
            v0 = (q == i) ? acc[(2 * i) >> 2][(2 * i) & 3]         : v0;
            v1 = (q == i) ? acc[(2 * i + 1) >> 2][(2 * i + 1) & 3] : v1;
        }
        const int oo = q >> 1, r0 = (q & 1) * 2;
        const float bias = (oo == 0) ? b0v.x : (oo == 1) ? b0v.y : (oo == 2) ? b0v.z : b0v.w;
        const int o = g * 4 + oo;
        h1s[r0][o]     = elu1(v0 + bias);
        h1s[r0 + 1][o] = elu1(v1 + bias);
    }
    barrier_lds();

    // ======== phase C: h2 = elu(h1 @ W1^T + b1) ========
    const unsigned short* wdp = wsb + W2BF_OFF + (gD * 2) * H2_ + q * 4;
    uint2 wd[8][2];    // W2 in full (32 VGPRs packed), issued mid-phase
    {
        float acc[4][4] = {};
        #pragma unroll
        for (int jj = 0; jj < 6; ++jj) {
            const uint2* wrow = (jj < 4) ? wc1[jj] : wc2[jj - 4];
            const int j = q * 4 + jj * 32;
            float4 a[RPB];
            #pragma unroll
            for (int r = 0; r < RPB; ++r)
                a[r] = *reinterpret_cast<const float4*>(&h1s[r][j]);
            #pragma unroll
            for (int oo = 0; oo < 4; ++oo) {
                const float2 p0 = bf2f(wrow[oo].x);
                const float2 p1 = bf2f(wrow[oo].y);
                #pragma unroll
                for (int r = 0; r < RPB; ++r) {
                    acc[oo][r] = fmaf(p0.x, a[r].x, acc[oo][r]);
                    acc[oo][r] = fmaf(p0.y, a[r].y, acc[oo][r]);
                    acc[oo][r] = fmaf(p1.x, a[r].z, acc[oo][r]);
                    acc[oo][r] = fmaf(p1.y, a[r].w, acc[oo][r]);
                }
            }
        }
        // ---- issue ALL W2 (32 VGPRs packed) ----
        #pragma unroll
        for (int jj = 0; jj < 8; ++jj)
            #pragma unroll
            for (int oo = 0; oo < 2; ++oo)
                wd[jj][oo] = *reinterpret_cast<const uint2*>(wdp + oo * H2_ + jj * 32);
        #pragma unroll
        for (int jj = 6; jj < 8; ++jj) {
            const uint2* wrow = wc2[jj - 4];
            const int j = q * 4 + jj * 32;
            float4 a[RPB];
            #pragma unroll
            for (int r = 0; r < RPB; ++r)
                a[r] = *reinterpret_cast<const float4*>(&h1s[r][j]);
            #pragma unroll
            for (int oo = 0; oo < 4; ++oo) {
                const float2 p0 = bf2f(wrow[oo].x);
                const float2 p1 = bf2f(wrow[oo].y);
                #pragma unroll
                for (int r = 0; r < RPB; ++r) {
                    acc[oo][r] = fmaf(p0.x, a[r].x, acc[oo][r]);
                    acc[oo][r] = fmaf(p0.y, a[r].y, acc[oo][r]);
                    acc[oo][r] = fmaf(p1.x, a[r].z, acc[oo][r]);
                    acc[oo][r] = fmaf(p1.y, a[r].w, acc[oo][r]);
                }
            }
        }
        #pragma unroll
        for (int oo = 0; oo < 4; ++oo)
            #pragma unroll
            for (int r = 0; r < RPB; ++r) acc[oo][r] = qsum8(acc[oo][r]);
        float v0 = acc[0][0], v1 = acc[0][1];
        #pragma unroll
        for (int i = 1; i < 8; ++i) {
            v0 = (q == i) ? acc[(2 * i) >> 2][(2 * i) & 3]         : v0;
            v1 = (q == i) ? acc[(2 * i + 1) >> 2][(2 * i + 1) & 3] : v1;
        }
        const int oo = q >> 1, r0 = (q & 1) * 2;
        const float bias = (oo == 0) ? b1v.x : (oo == 1) ? b1v.y : (oo == 2) ? b1v.z : b1v.w;
        const int o = g * 4 + oo;
        h2s[r0][o]     = elu1(v0 + bias);
        h2s[r0 + 1][o] = elu1(v1 + bias);
    }
    barrier_lds();

    // ======== phase D: ts[r][j] = h2s[r].W2[j,:] + b2[j] ========
    {
        float acc[2][4] = {};
        #pragma unroll
        for (int jj = 0; jj < 8; ++jj) {
            const int j = q * 4 + jj * 32;
            float4 a[RPB];
            #pragma unroll
            for (int r = 0; r < RPB; ++r)
                a[r] = *reinterpret_cast<const float4*>(&h2s[r][j]);
            #pragma unroll
            for (int oo = 0; oo < 2; ++oo) {
                const float2 p0 = bf2f(wd[jj][oo].x);
                const float2 p1 = bf2f(wd[jj][oo].y);
                #pragma unroll
                for (int r = 0; r < RPB; ++r) {
                    acc[oo][r] = fmaf(p0.x, a[r].x, acc[oo][r]);
                    acc[oo][r] = fmaf(p0.y, a[r].y, acc[oo][r]);
                    acc[oo][r] = fmaf(p1.x, a[r].z, acc[oo][r]);
                    acc[oo][r] = fmaf(p1.y, a[r].w, acc[oo][r]);
                }
            }
        }
        #pragma unroll
        for (int oo = 0; oo < 2; ++oo)
            #pragma unroll
            for (int r = 0; r < RPB; ++r) acc[oo][r] = qsum8(acc[oo][r]);
        float v = acc[0][0];
        #pragma unroll
        for (int i = 1; i < 8; ++i) v = (q == i) ? acc[i >> 2][i & 3] : v;
        const int oo = q >> 2, rr = q & 3;
        if (g < 63) ts[rr][g * 2 + oo] = v + (oo ? b2v.y : b2v.x);
        else        ts[rr][126 + oo]   = 0.0f;
    }
    barrier_lds();

    // ======== phase E: out[b,o] = sum_k ts[r][ej_k] ========
    if (tid < RPB * NOUT_) {
        const int r = tid / NOUT_, o = tid - r * NOUT_;
        out[(row0 + r) * NOUT_ + o] = ts[r][ej0] + ts[r][ej1] + ts[r][ej2];
    }
}

extern "C" void kernel_launch(void* const* d_in, const int* in_sizes, int n_in,
                              void* d_out, int out_size, void* d_ws, size_t ws_size,
                              hipStream_t stream) {
    const float* x   = (const float*)d_in[0];
    const float* W0  = (const float*)d_in[1];
    const float* b0  = (const float*)d_in[2];
    const float* W1  = (const float*)d_in[3];
    const float* b1  = (const float*)d_in[4];
    const float* W2  = (const float*)d_in[5];
    const float* b2  = (const float*)d_in[6];
    const int*  iidx = (const int*)d_in[7];
    const int*  oidx = (const int*)d_in[8];
    float* out = (float*)d_out;
    unsigned short* wsb = (unsigned short*)d_ws;

    wconv<<<512, 256, 0, stream>>>(W0, W1, W2, wsb);
    bim_fused<<<B_ / RPB, TPB, 0, stream>>>(x, wsb, b0, b1, b2, iidx, oidx, out);
}